// Round 10
// baseline (690.483 us; speedup 1.0000x reference)
//
#include <hip/hip_runtime.h>
#include <hip/hip_bf16.h>

#define N_NODES 100000
#define G_PART 16     // node groups; npg = 6250 -> 25 KB LDS hist
#define B_PART 48     // blocks per group for count/fill; grid 768 = 3/CU
#define NPG_PAD 6272  // LDS capacity (>= ceil(N/G_PART))
#define A_BLOCKS 1024 // partition blocks

// ---------------------------------------------------------------- CSR build
// R5: device atomics are memory-side -> LDS hist. R6: occupancy. R7: don't
// pollute L2 with the stream. R8: radix partition, edges read ~once.
__global__ __launch_bounds__(256) void partition_edges(
    const int* __restrict__ src, const int* __restrict__ dst, int E,
    int* __restrict__ bkt, unsigned int* __restrict__ gcur, int cap, int npg) {
    __shared__ int cnt16[G_PART];
    __shared__ unsigned int base16[G_PART];
    __shared__ unsigned int cur16[G_PART];
    int tid = threadIdx.x;
    if (tid < G_PART) cnt16[tid] = 0;
    __syncthreads();
    int per = (E + A_BLOCKS - 1) / A_BLOCKS;
    int beg = blockIdx.x * per;
    int end = min(beg + per, E);
    for (int i = beg + tid; i < end; i += 256) {
        int d = dst[i];
        atomicAdd(&cnt16[d / npg], 1);
    }
    __syncthreads();
    if (tid < G_PART) {
        base16[tid] = atomicAdd(&gcur[tid], (unsigned int)cnt16[tid]);
        cur16[tid] = 0;
    }
    __syncthreads();
    for (int i = beg + tid; i < end; i += 256) {
        int d = dst[i];
        int s = src[i];
        int g = d / npg;
        unsigned int p = base16[g] + atomicAdd(&cur16[g], 1u);
        bkt[(size_t)g * cap + p] = ((d - g * npg) << 17) | s;
    }
}

__global__ __launch_bounds__(256) void count_hist(const int* __restrict__ bkt,
                                                  const unsigned int* __restrict__ gcur,
                                                  int cap, int* __restrict__ partial,
                                                  int npg, int N) {
    __shared__ int hist[NPG_PAD];
    int g = blockIdx.x & (G_PART - 1);
    int b = blockIdx.x / G_PART;
    int tid = threadIdx.x;
    for (int i = tid; i < npg; i += 256) hist[i] = 0;
    __syncthreads();
    int len = (int)gcur[g];
    int per = (len + B_PART - 1) / B_PART;
    int ibeg = b * per;
    int iend = min(ibeg + per, len);
    const int* bp = bkt + (size_t)g * cap;
    for (int i = ibeg + tid; i < iend; i += 256) {
        int v = __builtin_nontemporal_load(bp + i);
        atomicAdd(&hist[v >> 17], 1);
    }
    __syncthreads();
    int base = (g * B_PART + b) * npg;
    for (int j = tid; j < npg; j += 256) partial[base + j] = hist[j];
}

__global__ __launch_bounds__(256) void scan_partials(int* __restrict__ partial,
                                                     int* __restrict__ cnt,
                                                     int npg, int N) {
    int n = blockIdx.x * 256 + threadIdx.x;
    if (n >= N) return;
    int g = n / npg;
    int i = n - g * npg;
    size_t base = (size_t)g * B_PART * npg + i;
    int run = 0;
#pragma unroll 4
    for (int b = 0; b < B_PART; ++b) {
        size_t idx = base + (size_t)b * npg;
        int t = partial[idx];
        partial[idx] = run;
        run += t;
    }
    cnt[n] = run;
}

__global__ __launch_bounds__(256) void fill_hist(const int* __restrict__ bkt,
                                                 const unsigned int* __restrict__ gcur,
                                                 int cap, const int* __restrict__ partial,
                                                 const int* __restrict__ row_off,
                                                 int* __restrict__ csr_src,
                                                 int npg, int N) {
    __shared__ int cur[NPG_PAD];
    int g = blockIdx.x & (G_PART - 1);
    int b = blockIdx.x / G_PART;
    int lo = g * npg;
    int tid = threadIdx.x;
    int pbase = (g * B_PART + b) * npg;
    for (int i = tid; i < npg && lo + i < N; i += 256)
        cur[i] = row_off[lo + i] + partial[pbase + i];
    __syncthreads();
    int len = (int)gcur[g];
    int per = (len + B_PART - 1) / B_PART;
    int ibeg = b * per;
    int iend = min(ibeg + per, len);
    const int* bp = bkt + (size_t)g * cap;
    for (int i = ibeg + tid; i < iend; i += 256) {
        int v = __builtin_nontemporal_load(bp + i);
        int p = atomicAdd(&cur[v >> 17], 1);
        csr_src[p] = v & 0x1FFFF;
    }
}

// ---------------- grid-parallel exclusive scan (3 kernels, 1024 elems/block)
#define SCHUNK 1024

__global__ __launch_bounds__(256) void scan_blocks(const int* __restrict__ cnt,
                                                   int* __restrict__ row_off,
                                                   int* __restrict__ block_sums, int n) {
    __shared__ int ts[256];
    int tid = threadIdx.x;
    int base = blockIdx.x * SCHUNK + tid * 4;
    int v[4];
    int s = 0;
#pragma unroll
    for (int j = 0; j < 4; ++j) {
        int i = base + j;
        v[j] = (i < n) ? cnt[i] : 0;
        s += v[j];
    }
    ts[tid] = s;
    __syncthreads();
    for (int off = 1; off < 256; off <<= 1) {
        int t = 0;
        if (tid >= off) t = ts[tid - off];
        __syncthreads();
        if (tid >= off) ts[tid] += t;
        __syncthreads();
    }
    int run = (tid > 0) ? ts[tid - 1] : 0;
    if (tid == 255) block_sums[blockIdx.x] = ts[255];
#pragma unroll
    for (int j = 0; j < 4; ++j) {
        int i = base + j;
        if (i < n) row_off[i] = run;
        run += v[j];
    }
}

__global__ __launch_bounds__(256) void scan_sums(int* __restrict__ block_sums, int nb,
                                                 int* __restrict__ row_off, int n) {
    __shared__ int ts[256];
    int tid = threadIdx.x;
    int v = (tid < nb) ? block_sums[tid] : 0;
    ts[tid] = v;
    __syncthreads();
    for (int off = 1; off < 256; off <<= 1) {
        int t = 0;
        if (tid >= off) t = ts[tid - off];
        __syncthreads();
        if (tid >= off) ts[tid] += t;
        __syncthreads();
    }
    if (tid < nb) block_sums[tid] = (tid > 0) ? ts[tid - 1] : 0;
    if (tid == 255) row_off[n] = ts[255];
}

__global__ __launch_bounds__(256) void scan_add(int* __restrict__ row_off,
                                                const int* __restrict__ block_sums, int n) {
    int tid = threadIdx.x;
    int off = block_sums[blockIdx.x];
    int base = blockIdx.x * SCHUNK + tid * 4;
#pragma unroll
    for (int j = 0; j < 4; ++j) {
        int i = base + j;
        if (i < n) row_off[i] += off;
    }
}

// ---------------------------------------------------------------- bf16 pack
__global__ __launch_bounds__(256) void pack_bf16(const float* __restrict__ in,
                                                 uint2* __restrict__ out, int n4) {
    int i = blockIdx.x * 256 + threadIdx.x;
    if (i >= n4) return;
    float4 v = *(const float4*)&in[(size_t)i * 4];
    __hip_bfloat162 p0 = __float22bfloat162_rn(make_float2(v.x, v.y));
    __hip_bfloat162 p1 = __float22bfloat162_rn(make_float2(v.z, v.w));
    uint2 o;
    o.x = *(const uint*)&p0;
    o.y = *(const uint*)&p1;
    out[i] = o;
}

// pack weights: Wc[n][k] bf16, k<128 -> Wl[n][k], else Wr[n][k-128]
__global__ __launch_bounds__(256) void pack_w(const float* __restrict__ Wl,
                                              const float* __restrict__ Wr,
                                              unsigned short* __restrict__ Wc) {
    int idx = blockIdx.x * 256 + threadIdx.x;
    if (idx >= 128 * 256) return;
    int n = idx >> 8, k = idx & 255;
    float v = (k < 128) ? Wl[n * 128 + k] : Wr[n * 128 + (k - 128)];
    __hip_bfloat16 b = __float2bfloat16(v);
    Wc[idx] = *(const unsigned short*)&b;
}

// ------------------------------------------------- mean aggregation, bf16 in/out
// R10: 4 edges per wave-load-instruction. lane = (q=lane>>4, c=lane&15):
// lane loads uint4 (16B = 8 bf16 cols) of edge-q's row -> 1 KiB/instruction,
// 4 rows in flight. Reduce across q with shfl_xor(32,16); lanes 0-15 store.
static __device__ inline float2 unpack2(uint v) {
    float2 r;
    r.x = __uint_as_float(v << 16);
    r.y = __uint_as_float(v & 0xffff0000u);
    return r;
}

__global__ __launch_bounds__(256) void agg_bf16(const uint4* __restrict__ featq,
                                                const int* __restrict__ row_off,
                                                const int* __restrict__ csr,
                                                uint4* __restrict__ outq, int M) {
    int node = blockIdx.x * 4 + (threadIdx.x >> 6);
    if (node >= M) return;
    int lane = threadIdx.x & 63;
    int q = lane >> 4;    // edge slot 0..3
    int c = lane & 15;    // column chunk (8 bf16)
    int beg = row_off[node], end = row_off[node + 1];
    float a0 = 0.f, a1 = 0.f, a2 = 0.f, a3 = 0.f;
    float a4 = 0.f, a5 = 0.f, a6 = 0.f, a7 = 0.f;
    int i = beg;
    for (; i + 4 <= end; i += 4) {
        int s = __builtin_nontemporal_load(csr + i + q);
        uint4 v = featq[(size_t)s * 16 + c];
        float2 f0 = unpack2(v.x), f1 = unpack2(v.y);
        float2 f2 = unpack2(v.z), f3 = unpack2(v.w);
        a0 += f0.x; a1 += f0.y; a2 += f1.x; a3 += f1.y;
        a4 += f2.x; a5 += f2.y; a6 += f3.x; a7 += f3.y;
    }
    int rem = end - i;   // 0..3
    if (rem > 0) {
        int idx = i + q;
        int cl = (idx < end) ? idx : (end - 1);
        int s = __builtin_nontemporal_load(csr + cl);
        uint4 v = featq[(size_t)s * 16 + c];
        if (idx < end) {
            float2 f0 = unpack2(v.x), f1 = unpack2(v.y);
            float2 f2 = unpack2(v.z), f3 = unpack2(v.w);
            a0 += f0.x; a1 += f0.y; a2 += f1.x; a3 += f1.y;
            a4 += f2.x; a5 += f2.y; a6 += f3.x; a7 += f3.y;
        }
    }
    // reduce across the 4 edge slots (lane bits 5:4)
    a0 += __shfl_xor(a0, 32); a1 += __shfl_xor(a1, 32);
    a2 += __shfl_xor(a2, 32); a3 += __shfl_xor(a3, 32);
    a4 += __shfl_xor(a4, 32); a5 += __shfl_xor(a5, 32);
    a6 += __shfl_xor(a6, 32); a7 += __shfl_xor(a7, 32);
    a0 += __shfl_xor(a0, 16); a1 += __shfl_xor(a1, 16);
    a2 += __shfl_xor(a2, 16); a3 += __shfl_xor(a3, 16);
    a4 += __shfl_xor(a4, 16); a5 += __shfl_xor(a5, 16);
    a6 += __shfl_xor(a6, 16); a7 += __shfl_xor(a7, 16);
    if (q == 0) {
        float inv = (end > beg) ? 1.0f / (float)(end - beg) : 0.0f;
        __hip_bfloat162 p0 = __float22bfloat162_rn(make_float2(a0 * inv, a1 * inv));
        __hip_bfloat162 p1 = __float22bfloat162_rn(make_float2(a2 * inv, a3 * inv));
        __hip_bfloat162 p2 = __float22bfloat162_rn(make_float2(a4 * inv, a5 * inv));
        __hip_bfloat162 p3 = __float22bfloat162_rn(make_float2(a6 * inv, a7 * inv));
        uint4 o;
        o.x = *(const uint*)&p0;
        o.y = *(const uint*)&p1;
        o.z = *(const uint*)&p2;
        o.w = *(const uint*)&p3;
        outq[(size_t)node * 16 + c] = o;
    }
}

// --------------------------------------------- MFMA bf16 GEMM (LDS-free)
// out[m][n] = act(sum_k [Aagg|Aself][m][k] * Wc[n][k] + bias[n])
typedef __attribute__((ext_vector_type(8))) short bfrag8;
typedef __attribute__((ext_vector_type(4))) float f32x4;

__global__ __launch_bounds__(256) void gemm_mfma(
    const unsigned short* __restrict__ Aagg,   // [M][128] bf16
    const unsigned short* __restrict__ Aself,  // [M][128] bf16
    const unsigned short* __restrict__ Wc,     // [128][256] bf16
    const float* __restrict__ bias,            // [128]
    float* __restrict__ outf,                  // nullable [M][128] fp32
    unsigned short* __restrict__ outb,         // nullable [M][128] bf16
    int M, int relu) {
    int wave = threadIdx.x >> 6;
    int lane = threadIdx.x & 63;
    int m0 = blockIdx.x * 64 + wave * 16;
    int mrow = lane & 15;
    int quad = lane >> 4;
    int row = m0 + mrow;
    int rclamp = (row < M) ? row : 0;

    f32x4 acc[8];
#pragma unroll
    for (int t = 0; t < 8; ++t) acc[t] = (f32x4){0.f, 0.f, 0.f, 0.f};

    const unsigned short* arow0 = Aagg + (size_t)rclamp * 128;
    const unsigned short* arow1 = Aself + (size_t)rclamp * 128;
#pragma unroll
    for (int ks = 0; ks < 8; ++ks) {
        int k0 = ks * 32;
        const unsigned short* ap =
            (k0 < 128) ? (arow0 + k0 + quad * 8) : (arow1 + (k0 - 128) + quad * 8);
        bfrag8 af = *(const bfrag8*)ap;
#pragma unroll
        for (int t = 0; t < 8; ++t) {
            const unsigned short* bp = Wc + (size_t)(t * 16 + mrow) * 256 + k0 + quad * 8;
            bfrag8 bf = *(const bfrag8*)bp;
            acc[t] = __builtin_amdgcn_mfma_f32_16x16x32_bf16(af, bf, acc[t], 0, 0, 0);
        }
    }
#pragma unroll
    for (int t = 0; t < 8; ++t) {
        int col = t * 16 + mrow;
        float bcol = bias[col];
#pragma unroll
        for (int r = 0; r < 4; ++r) {
            int orow = m0 + quad * 4 + r;
            if (orow < M) {
                float v = acc[t][r] + bcol;
                if (relu) v = fmaxf(v, 0.f);
                if (outf) outf[(size_t)orow * 128 + col] = v;
                if (outb) {
                    __hip_bfloat16 hb = __float2bfloat16(v);
                    outb[(size_t)orow * 128 + col] = *(const unsigned short*)&hb;
                }
            }
        }
    }
}

// ------------------------------------- layer 3 transform: zr[n][0..5]=h@Wl3^T, [6..11]=h@Wr3^T+b3
__global__ __launch_bounds__(256) void lin3_kernel(const float* __restrict__ h,
                                                   const float* __restrict__ Wl,
                                                   const float* __restrict__ Wr,
                                                   const float* __restrict__ b3,
                                                   float* __restrict__ zr, int M) {
    __shared__ float Ws[12][129];
    __shared__ float hs[16][132];
    int tid = threadIdx.x;
    for (int f = tid; f < 12 * 128; f += 256) {
        int j = f >> 7, k = f & 127;
        Ws[j][k] = (j < 6) ? Wl[j * 128 + k] : Wr[(j - 6) * 128 + k];
    }
    int node0 = blockIdx.x * 16;
#pragma unroll
    for (int t = 0; t < 2; ++t) {
        int f = tid + t * 256;
        int r = f >> 5;
        int c4 = (f & 31) * 4;
        int gn = node0 + r;
        float4 v = make_float4(0.f, 0.f, 0.f, 0.f);
        if (gn < M) v = *(const float4*)&h[(size_t)gn * 128 + c4];
        *(float4*)&hs[r][c4] = v;
    }
    __syncthreads();
    int ln = tid >> 4;
    int j = tid & 15;
    int gn = node0 + ln;
    if (j < 12 && gn < M) {
        float acc = 0.f;
#pragma unroll
        for (int k = 0; k < 128; ++k) acc += hs[ln][k] * Ws[j][k];
        if (j >= 6) acc += b3[j - 6];
        zr[(size_t)gn * 12 + j] = acc;
    }
}

// ------------------------------------------- final: out[n][j] = mean_s z[s][j] + r[n][j]
__global__ void out_kernel(const float* __restrict__ zr, const int* __restrict__ row_off,
                           const int* __restrict__ csr, float* __restrict__ out, int M) {
    int idx = blockIdx.x * blockDim.x + threadIdx.x;
    int node = idx >> 3;
    int j = idx & 7;
    if (node >= M || j >= 6) return;
    int beg = row_off[node], end = row_off[node + 1];
    float acc = 0.f;
    for (int i = beg; i < end; ++i) {
        int s = csr[i];
        acc += zr[(size_t)s * 12 + j];
    }
    float inv = (end > beg) ? 1.0f / (float)(end - beg) : 0.0f;
    out[(size_t)node * 6 + j] = acc * inv + zr[(size_t)node * 12 + 6 + j];
}

// ---------------------------------------------------------------- launch
static inline size_t align_up(size_t x, size_t a) { return (x + a - 1) & ~(a - 1); }

extern "C" void kernel_launch(void* const* d_in, const int* in_sizes, int n_in,
                              void* d_out, int out_size, void* d_ws, size_t ws_size,
                              hipStream_t stream) {
    const float* x = (const float*)d_in[0];
    const int* ei = (const int*)d_in[1];
    const float* Wl1 = (const float*)d_in[2];
    const float* Wr1 = (const float*)d_in[3];
    const float* b1 = (const float*)d_in[4];
    const float* Wl2 = (const float*)d_in[5];
    const float* Wr2 = (const float*)d_in[6];
    const float* b2 = (const float*)d_in[7];
    const float* Wl3 = (const float*)d_in[8];
    const float* Wr3 = (const float*)d_in[9];
    const float* b3 = (const float*)d_in[10];

    const int N = in_sizes[0] / 128;   // 100000
    const int E = in_sizes[1] / 2;     // 3200000
    const int* src = ei;
    const int* dst = ei + E;

    // workspace layout
    char* ws = (char*)d_ws;
    size_t off = 0;
    int* cnt = (int*)(ws + off);        off = align_up(off + (size_t)N * 4, 512);
    int* row_off = (int*)(ws + off);    off = align_up(off + (size_t)(N + 1) * 4, 512);
    int* block_sums = (int*)(ws + off); off = align_up(off + 512 * 4, 512);
    unsigned int* gcur = (unsigned int*)(ws + off); off = align_up(off + 64 * 4, 512);
    unsigned short* Wc1 = (unsigned short*)(ws + off); off = align_up(off + 128 * 256 * 2, 512);
    unsigned short* Wc2 = (unsigned short*)(ws + off); off = align_up(off + 128 * 256 * 2, 512);
    int* csr_src = (int*)(ws + off);    off = align_up(off + (size_t)E * 4, 512);
    float* slotA = (float*)(ws + off);  off = align_up(off + (size_t)N * 128 * 4, 512);
    float* slotB = (float*)(ws + off);  off = align_up(off + (size_t)N * 128 * 4, 512);
    float* h2 = (float*)(ws + off);     off = align_up(off + (size_t)N * 128 * 4, 512);
    float* zr = (float*)(ws + off);     off = align_up(off + (size_t)N * 12 * 4, 512);
    uint2* h1b = (uint2*)(ws + off);    off = align_up(off + (size_t)N * 128 * 2, 512);
    // aliases (all lifetimes disjoint):
    //  partial on slotA [count..fill];  aggb on slotA [agg1..gemm1, agg2..gemm2]
    //  bkt on slotB [partition..fill]
    //  xb on h2 [pack..gemm1]; h2 written at gemm2
    int* partial = (int*)slotA;               // 16*48*6250*4 = 19.2 MB
    uint* aggb = (uint*)slotA;                // 25.6 MB
    const int cap = 210000;
    int* bkt = (int*)slotB;                   // 13.44 MB
    uint2* xb = (uint2*)h2;
    (void)ws_size;

    // --- CSR build: radix partition + LDS histogram, no per-edge global atomics
    const int npg = (N + G_PART - 1) / G_PART;       // 6250
    const int build_grid = G_PART * B_PART;          // 768

    hipMemsetAsync(gcur, 0, G_PART * 4, stream);
    partition_edges<<<A_BLOCKS, 256, 0, stream>>>(src, dst, E, bkt, gcur, cap, npg);
    count_hist<<<build_grid, 256, 0, stream>>>(bkt, gcur, cap, partial, npg, N);
    scan_partials<<<(N + 255) / 256, 256, 0, stream>>>(partial, cnt, npg, N);

    const int nscan = (N + SCHUNK - 1) / SCHUNK;
    scan_blocks<<<nscan, 256, 0, stream>>>(cnt, row_off, block_sums, N);
    scan_sums<<<1, 256, 0, stream>>>(block_sums, nscan, row_off, N);
    scan_add<<<nscan, 256, 0, stream>>>(row_off, block_sums, N);

    fill_hist<<<build_grid, 256, 0, stream>>>(bkt, gcur, cap, partial, row_off,
                                              csr_src, npg, N);

    // packs
    const int n4 = N * 32;
    pack_bf16<<<(n4 + 255) / 256, 256, 0, stream>>>(x, xb, n4);
    pack_w<<<128, 256, 0, stream>>>(Wl1, Wr1, Wc1);
    pack_w<<<128, 256, 0, stream>>>(Wl2, Wr2, Wc2);

    int aggGrid = (N + 3) / 4;
    int gemmGrid = (N + 63) / 64;

    // layer 1: agg(bf16)->aggb; MFMA gemm -> h1b (bf16 only)
    agg_bf16<<<aggGrid, 256, 0, stream>>>((const uint4*)xb, row_off, csr_src,
                                          (uint4*)aggb, N);
    gemm_mfma<<<gemmGrid, 256, 0, stream>>>((const unsigned short*)aggb,
                                            (const unsigned short*)xb, Wc1, b1,
                                            nullptr, (unsigned short*)h1b, N, 1);
    // layer 2: agg(bf16 h1b)->aggb; MFMA gemm -> h2 (fp32 for lin3)
    agg_bf16<<<aggGrid, 256, 0, stream>>>((const uint4*)h1b, row_off, csr_src,
                                          (uint4*)aggb, N);
    gemm_mfma<<<gemmGrid, 256, 0, stream>>>((const unsigned short*)aggb,
                                            (const unsigned short*)h1b, Wc2, b2,
                                            h2, nullptr, N, 1);
    // layer 3
    lin3_kernel<<<(N + 15) / 16, 256, 0, stream>>>(h2, Wl3, Wr3, b3, zr, N);
    out_kernel<<<(N * 8 + 255) / 256, 256, 0, stream>>>(zr, row_off, csr_src, (float*)d_out, N);
}

// Round 11
// 651.246 us; speedup vs baseline: 1.0602x; 1.0602x over previous
//
#include <hip/hip_runtime.h>
#include <hip/hip_bf16.h>

#define N_NODES 100000
#define G_PART 16     // node groups; npg = 6250 -> 25 KB LDS hist
#define B_PART 96     // blocks per group; grid 1536 = 6 blocks/CU (LDS cap)
#define NPG_PAD 6272  // LDS capacity (>= ceil(N/G_PART))
#define A_BLOCKS 1024 // partition blocks

// ---------------------------------------------------------------- CSR build
// R5: device atomics are memory-side -> LDS hist. R6: occupancy. R7: don't
// pollute L2 with the stream. R8: radix partition, edges read ~once.
// R11: count/fill grid 768->1536 (LDS allows 6 blocks/CU; was running 3).
__global__ __launch_bounds__(256) void partition_edges(
    const int* __restrict__ src, const int* __restrict__ dst, int E,
    int* __restrict__ bkt, unsigned int* __restrict__ gcur, int cap, int npg) {
    __shared__ int cnt16[G_PART];
    __shared__ unsigned int base16[G_PART];
    __shared__ unsigned int cur16[G_PART];
    int tid = threadIdx.x;
    if (tid < G_PART) cnt16[tid] = 0;
    __syncthreads();
    int per = (E + A_BLOCKS - 1) / A_BLOCKS;
    int beg = blockIdx.x * per;
    int end = min(beg + per, E);
    for (int i = beg + tid; i < end; i += 256) {
        int d = dst[i];
        atomicAdd(&cnt16[d / npg], 1);
    }
    __syncthreads();
    if (tid < G_PART) {
        base16[tid] = atomicAdd(&gcur[tid], (unsigned int)cnt16[tid]);
        cur16[tid] = 0;
    }
    __syncthreads();
    for (int i = beg + tid; i < end; i += 256) {
        int d = dst[i];
        int s = src[i];
        int g = d / npg;
        unsigned int p = base16[g] + atomicAdd(&cur16[g], 1u);
        bkt[(size_t)g * cap + p] = ((d - g * npg) << 17) | s;
    }
}

__global__ __launch_bounds__(256) void count_hist(const int* __restrict__ bkt,
                                                  const unsigned int* __restrict__ gcur,
                                                  int cap, int* __restrict__ partial,
                                                  int npg, int N) {
    __shared__ int hist[NPG_PAD];
    int g = blockIdx.x & (G_PART - 1);
    int b = blockIdx.x / G_PART;
    int tid = threadIdx.x;
    for (int i = tid; i < npg; i += 256) hist[i] = 0;
    __syncthreads();
    int len = (int)gcur[g];
    int per = (len + B_PART - 1) / B_PART;
    int ibeg = b * per;
    int iend = min(ibeg + per, len);
    const int* bp = bkt + (size_t)g * cap;
    for (int i = ibeg + tid; i < iend; i += 256) {
        int v = __builtin_nontemporal_load(bp + i);
        atomicAdd(&hist[v >> 17], 1);
    }
    __syncthreads();
    int base = (g * B_PART + b) * npg;
    for (int j = tid; j < npg; j += 256) partial[base + j] = hist[j];
}

__global__ __launch_bounds__(256) void scan_partials(int* __restrict__ partial,
                                                     int* __restrict__ cnt,
                                                     int npg, int N) {
    int n = blockIdx.x * 256 + threadIdx.x;
    if (n >= N) return;
    int g = n / npg;
    int i = n - g * npg;
    size_t base = (size_t)g * B_PART * npg + i;
    int run = 0;
#pragma unroll 4
    for (int b = 0; b < B_PART; ++b) {
        size_t idx = base + (size_t)b * npg;
        int t = partial[idx];
        partial[idx] = run;
        run += t;
    }
    cnt[n] = run;
}

__global__ __launch_bounds__(256) void fill_hist(const int* __restrict__ bkt,
                                                 const unsigned int* __restrict__ gcur,
                                                 int cap, const int* __restrict__ partial,
                                                 const int* __restrict__ row_off,
                                                 int* __restrict__ csr_src,
                                                 int npg, int N) {
    __shared__ int cur[NPG_PAD];
    int g = blockIdx.x & (G_PART - 1);
    int b = blockIdx.x / G_PART;
    int lo = g * npg;
    int tid = threadIdx.x;
    int pbase = (g * B_PART + b) * npg;
    for (int i = tid; i < npg && lo + i < N; i += 256)
        cur[i] = row_off[lo + i] + partial[pbase + i];
    __syncthreads();
    int len = (int)gcur[g];
    int per = (len + B_PART - 1) / B_PART;
    int ibeg = b * per;
    int iend = min(ibeg + per, len);
    const int* bp = bkt + (size_t)g * cap;
    for (int i = ibeg + tid; i < iend; i += 256) {
        int v = __builtin_nontemporal_load(bp + i);
        int p = atomicAdd(&cur[v >> 17], 1);
        csr_src[p] = v & 0x1FFFF;
    }
}

// ---------------- grid-parallel exclusive scan (3 kernels, 1024 elems/block)
#define SCHUNK 1024

__global__ __launch_bounds__(256) void scan_blocks(const int* __restrict__ cnt,
                                                   int* __restrict__ row_off,
                                                   int* __restrict__ block_sums, int n) {
    __shared__ int ts[256];
    int tid = threadIdx.x;
    int base = blockIdx.x * SCHUNK + tid * 4;
    int v[4];
    int s = 0;
#pragma unroll
    for (int j = 0; j < 4; ++j) {
        int i = base + j;
        v[j] = (i < n) ? cnt[i] : 0;
        s += v[j];
    }
    ts[tid] = s;
    __syncthreads();
    for (int off = 1; off < 256; off <<= 1) {
        int t = 0;
        if (tid >= off) t = ts[tid - off];
        __syncthreads();
        if (tid >= off) ts[tid] += t;
        __syncthreads();
    }
    int run = (tid > 0) ? ts[tid - 1] : 0;
    if (tid == 255) block_sums[blockIdx.x] = ts[255];
#pragma unroll
    for (int j = 0; j < 4; ++j) {
        int i = base + j;
        if (i < n) row_off[i] = run;
        run += v[j];
    }
}

__global__ __launch_bounds__(256) void scan_sums(int* __restrict__ block_sums, int nb,
                                                 int* __restrict__ row_off, int n) {
    __shared__ int ts[256];
    int tid = threadIdx.x;
    int v = (tid < nb) ? block_sums[tid] : 0;
    ts[tid] = v;
    __syncthreads();
    for (int off = 1; off < 256; off <<= 1) {
        int t = 0;
        if (tid >= off) t = ts[tid - off];
        __syncthreads();
        if (tid >= off) ts[tid] += t;
        __syncthreads();
    }
    if (tid < nb) block_sums[tid] = (tid > 0) ? ts[tid - 1] : 0;
    if (tid == 255) row_off[n] = ts[255];
}

__global__ __launch_bounds__(256) void scan_add(int* __restrict__ row_off,
                                                const int* __restrict__ block_sums, int n) {
    int tid = threadIdx.x;
    int off = block_sums[blockIdx.x];
    int base = blockIdx.x * SCHUNK + tid * 4;
#pragma unroll
    for (int j = 0; j < 4; ++j) {
        int i = base + j;
        if (i < n) row_off[i] += off;
    }
}

// ---------------------------------------------------------------- bf16 pack
__global__ __launch_bounds__(256) void pack_bf16(const float* __restrict__ in,
                                                 uint2* __restrict__ out, int n4) {
    int i = blockIdx.x * 256 + threadIdx.x;
    if (i >= n4) return;
    float4 v = *(const float4*)&in[(size_t)i * 4];
    __hip_bfloat162 p0 = __float22bfloat162_rn(make_float2(v.x, v.y));
    __hip_bfloat162 p1 = __float22bfloat162_rn(make_float2(v.z, v.w));
    uint2 o;
    o.x = *(const uint*)&p0;
    o.y = *(const uint*)&p1;
    out[i] = o;
}

// pack weights: Wc[n][k] bf16, k<128 -> Wl[n][k], else Wr[n][k-128]
__global__ __launch_bounds__(256) void pack_w(const float* __restrict__ Wl,
                                              const float* __restrict__ Wr,
                                              unsigned short* __restrict__ Wc) {
    int idx = blockIdx.x * 256 + threadIdx.x;
    if (idx >= 128 * 256) return;
    int n = idx >> 8, k = idx & 255;
    float v = (k < 128) ? Wl[n * 128 + k] : Wr[n * 128 + (k - 128)];
    __hip_bfloat16 b = __float2bfloat16(v);
    Wc[idx] = *(const unsigned short*)&b;
}

// ------------------------------------------------- mean aggregation, bf16 in/out
// R11: reverted to the R9 form — R10's 4-row-per-instruction variant proved
// the gather is FETCH-byte-bound (~3.2 TB/s random-256B fabric rate), not
// instruction-bound, and its remainder path added ~30MB of extra misses.
static __device__ inline float2 unpack2(uint v) {
    float2 r;
    r.x = __uint_as_float(v << 16);
    r.y = __uint_as_float(v & 0xffff0000u);
    return r;
}

__global__ __launch_bounds__(256) void agg_bf16(const uint* __restrict__ featb,
                                                const int* __restrict__ row_off,
                                                const int* __restrict__ csr,
                                                uint* __restrict__ outb, int M) {
    int node = blockIdx.x * 4 + (threadIdx.x >> 6);
    if (node >= M) return;
    int lane = threadIdx.x & 63;
    int beg = row_off[node], end = row_off[node + 1];
    float sx = 0.f, sy = 0.f;
    int i = beg;
    for (; i + 4 <= end; i += 4) {
        int s0 = csr[i], s1 = csr[i + 1], s2 = csr[i + 2], s3 = csr[i + 3];
        uint v0 = featb[(size_t)s0 * 64 + lane];
        uint v1 = featb[(size_t)s1 * 64 + lane];
        uint v2 = featb[(size_t)s2 * 64 + lane];
        uint v3 = featb[(size_t)s3 * 64 + lane];
        float2 f0 = unpack2(v0), f1 = unpack2(v1), f2 = unpack2(v2), f3 = unpack2(v3);
        sx += f0.x + f1.x + f2.x + f3.x;
        sy += f0.y + f1.y + f2.y + f3.y;
    }
    for (; i < end; ++i) {
        uint v = featb[(size_t)csr[i] * 64 + lane];
        float2 f = unpack2(v);
        sx += f.x;
        sy += f.y;
    }
    float inv = (end > beg) ? 1.0f / (float)(end - beg) : 0.0f;
    __hip_bfloat162 p = __float22bfloat162_rn(make_float2(sx * inv, sy * inv));
    outb[(size_t)node * 64 + lane] = *(const uint*)&p;
}

// --------------------------------------------- MFMA bf16 GEMM (LDS-free)
// out[m][n] = act(sum_k [Aagg|Aself][m][k] * Wc[n][k] + bias[n])
typedef __attribute__((ext_vector_type(8))) short bfrag8;
typedef __attribute__((ext_vector_type(4))) float f32x4;

__global__ __launch_bounds__(256) void gemm_mfma(
    const unsigned short* __restrict__ Aagg,   // [M][128] bf16
    const unsigned short* __restrict__ Aself,  // [M][128] bf16
    const unsigned short* __restrict__ Wc,     // [128][256] bf16
    const float* __restrict__ bias,            // [128]
    float* __restrict__ outf,                  // nullable [M][128] fp32
    unsigned short* __restrict__ outb,         // nullable [M][128] bf16
    int M, int relu) {
    int wave = threadIdx.x >> 6;
    int lane = threadIdx.x & 63;
    int m0 = blockIdx.x * 64 + wave * 16;
    int mrow = lane & 15;
    int quad = lane >> 4;
    int row = m0 + mrow;
    int rclamp = (row < M) ? row : 0;

    f32x4 acc[8];
#pragma unroll
    for (int t = 0; t < 8; ++t) acc[t] = (f32x4){0.f, 0.f, 0.f, 0.f};

    const unsigned short* arow0 = Aagg + (size_t)rclamp * 128;
    const unsigned short* arow1 = Aself + (size_t)rclamp * 128;
#pragma unroll
    for (int ks = 0; ks < 8; ++ks) {
        int k0 = ks * 32;
        const unsigned short* ap =
            (k0 < 128) ? (arow0 + k0 + quad * 8) : (arow1 + (k0 - 128) + quad * 8);
        bfrag8 af = *(const bfrag8*)ap;
#pragma unroll
        for (int t = 0; t < 8; ++t) {
            const unsigned short* bp = Wc + (size_t)(t * 16 + mrow) * 256 + k0 + quad * 8;
            bfrag8 bf = *(const bfrag8*)bp;
            acc[t] = __builtin_amdgcn_mfma_f32_16x16x32_bf16(af, bf, acc[t], 0, 0, 0);
        }
    }
#pragma unroll
    for (int t = 0; t < 8; ++t) {
        int col = t * 16 + mrow;
        float bcol = bias[col];
#pragma unroll
        for (int r = 0; r < 4; ++r) {
            int orow = m0 + quad * 4 + r;
            if (orow < M) {
                float v = acc[t][r] + bcol;
                if (relu) v = fmaxf(v, 0.f);
                if (outf) outf[(size_t)orow * 128 + col] = v;
                if (outb) {
                    __hip_bfloat16 hb = __float2bfloat16(v);
                    outb[(size_t)orow * 128 + col] = *(const unsigned short*)&hb;
                }
            }
        }
    }
}

// ------------------------------------- layer 3 transform: zr[n][0..5]=h@Wl3^T, [6..11]=h@Wr3^T+b3
__global__ __launch_bounds__(256) void lin3_kernel(const float* __restrict__ h,
                                                   const float* __restrict__ Wl,
                                                   const float* __restrict__ Wr,
                                                   const float* __restrict__ b3,
                                                   float* __restrict__ zr, int M) {
    __shared__ float Ws[12][129];
    __shared__ float hs[16][132];
    int tid = threadIdx.x;
    for (int f = tid; f < 12 * 128; f += 256) {
        int j = f >> 7, k = f & 127;
        Ws[j][k] = (j < 6) ? Wl[j * 128 + k] : Wr[(j - 6) * 128 + k];
    }
    int node0 = blockIdx.x * 16;
#pragma unroll
    for (int t = 0; t < 2; ++t) {
        int f = tid + t * 256;
        int r = f >> 5;
        int c4 = (f & 31) * 4;
        int gn = node0 + r;
        float4 v = make_float4(0.f, 0.f, 0.f, 0.f);
        if (gn < M) v = *(const float4*)&h[(size_t)gn * 128 + c4];
        *(float4*)&hs[r][c4] = v;
    }
    __syncthreads();
    int ln = tid >> 4;
    int j = tid & 15;
    int gn = node0 + ln;
    if (j < 12 && gn < M) {
        float acc = 0.f;
#pragma unroll
        for (int k = 0; k < 128; ++k) acc += hs[ln][k] * Ws[j][k];
        if (j >= 6) acc += b3[j - 6];
        zr[(size_t)gn * 12 + j] = acc;
    }
}

// ------------------------------------------- final: out[n][j] = mean_s z[s][j] + r[n][j]
// R11: 4x manual unroll -> 4 independent zr gathers in flight per thread.
__global__ void out_kernel(const float* __restrict__ zr, const int* __restrict__ row_off,
                           const int* __restrict__ csr, float* __restrict__ out, int M) {
    int idx = blockIdx.x * blockDim.x + threadIdx.x;
    int node = idx >> 3;
    int j = idx & 7;
    if (node >= M || j >= 6) return;
    int beg = row_off[node], end = row_off[node + 1];
    float acc = 0.f;
    int i = beg;
    for (; i + 4 <= end; i += 4) {
        int s0 = csr[i], s1 = csr[i + 1], s2 = csr[i + 2], s3 = csr[i + 3];
        float z0 = zr[(size_t)s0 * 12 + j];
        float z1 = zr[(size_t)s1 * 12 + j];
        float z2 = zr[(size_t)s2 * 12 + j];
        float z3 = zr[(size_t)s3 * 12 + j];
        acc += z0 + z1 + z2 + z3;
    }
    for (; i < end; ++i) acc += zr[(size_t)csr[i] * 12 + j];
    float inv = (end > beg) ? 1.0f / (float)(end - beg) : 0.0f;
    out[(size_t)node * 6 + j] = acc * inv + zr[(size_t)node * 12 + 6 + j];
}

// ---------------------------------------------------------------- launch
static inline size_t align_up(size_t x, size_t a) { return (x + a - 1) & ~(a - 1); }

extern "C" void kernel_launch(void* const* d_in, const int* in_sizes, int n_in,
                              void* d_out, int out_size, void* d_ws, size_t ws_size,
                              hipStream_t stream) {
    const float* x = (const float*)d_in[0];
    const int* ei = (const int*)d_in[1];
    const float* Wl1 = (const float*)d_in[2];
    const float* Wr1 = (const float*)d_in[3];
    const float* b1 = (const float*)d_in[4];
    const float* Wl2 = (const float*)d_in[5];
    const float* Wr2 = (const float*)d_in[6];
    const float* b2 = (const float*)d_in[7];
    const float* Wl3 = (const float*)d_in[8];
    const float* Wr3 = (const float*)d_in[9];
    const float* b3 = (const float*)d_in[10];

    const int N = in_sizes[0] / 128;   // 100000
    const int E = in_sizes[1] / 2;     // 3200000
    const int* src = ei;
    const int* dst = ei + E;

    // workspace layout
    char* ws = (char*)d_ws;
    size_t off = 0;
    int* cnt = (int*)(ws + off);        off = align_up(off + (size_t)N * 4, 512);
    int* row_off = (int*)(ws + off);    off = align_up(off + (size_t)(N + 1) * 4, 512);
    int* block_sums = (int*)(ws + off); off = align_up(off + 512 * 4, 512);
    unsigned int* gcur = (unsigned int*)(ws + off); off = align_up(off + 64 * 4, 512);
    unsigned short* Wc1 = (unsigned short*)(ws + off); off = align_up(off + 128 * 256 * 2, 512);
    unsigned short* Wc2 = (unsigned short*)(ws + off); off = align_up(off + 128 * 256 * 2, 512);
    int* csr_src = (int*)(ws + off);    off = align_up(off + (size_t)E * 4, 512);
    float* slotA = (float*)(ws + off);  off = align_up(off + (size_t)N * 128 * 4, 512);
    float* slotB = (float*)(ws + off);  off = align_up(off + (size_t)N * 128 * 4, 512);
    float* h2 = (float*)(ws + off);     off = align_up(off + (size_t)N * 128 * 4, 512);
    float* zr = (float*)(ws + off);     off = align_up(off + (size_t)N * 12 * 4, 512);
    uint2* h1b = (uint2*)(ws + off);    off = align_up(off + (size_t)N * 128 * 2, 512);
    // aliases (all lifetimes disjoint):
    //  partial on slotA [count..fill] (16*96*6250*4 = 38.4 MB <= 51.2 MB)
    //  aggb on slotA [agg1..gemm1, agg2..gemm2]
    //  bkt on slotB [partition..fill]
    //  xb on h2 [pack..gemm1]; h2 written at gemm2
    int* partial = (int*)slotA;
    uint* aggb = (uint*)slotA;
    const int cap = 210000;
    int* bkt = (int*)slotB;                   // 13.44 MB
    uint2* xb = (uint2*)h2;
    (void)ws_size;

    // --- CSR build: radix partition + LDS histogram, no per-edge global atomics
    const int npg = (N + G_PART - 1) / G_PART;       // 6250
    const int build_grid = G_PART * B_PART;          // 1536 = 6 blocks/CU

    hipMemsetAsync(gcur, 0, G_PART * 4, stream);
    partition_edges<<<A_BLOCKS, 256, 0, stream>>>(src, dst, E, bkt, gcur, cap, npg);
    count_hist<<<build_grid, 256, 0, stream>>>(bkt, gcur, cap, partial, npg, N);
    scan_partials<<<(N + 255) / 256, 256, 0, stream>>>(partial, cnt, npg, N);

    const int nscan = (N + SCHUNK - 1) / SCHUNK;
    scan_blocks<<<nscan, 256, 0, stream>>>(cnt, row_off, block_sums, N);
    scan_sums<<<1, 256, 0, stream>>>(block_sums, nscan, row_off, N);
    scan_add<<<nscan, 256, 0, stream>>>(row_off, block_sums, N);

    fill_hist<<<build_grid, 256, 0, stream>>>(bkt, gcur, cap, partial, row_off,
                                              csr_src, npg, N);

    // packs
    const int n4 = N * 32;
    pack_bf16<<<(n4 + 255) / 256, 256, 0, stream>>>(x, xb, n4);
    pack_w<<<128, 256, 0, stream>>>(Wl1, Wr1, Wc1);
    pack_w<<<128, 256, 0, stream>>>(Wl2, Wr2, Wc2);

    int aggGrid = (N + 3) / 4;
    int gemmGrid = (N + 63) / 64;

    // layer 1: agg(bf16)->aggb; MFMA gemm -> h1b (bf16 only)
    agg_bf16<<<aggGrid, 256, 0, stream>>>((const uint*)xb, row_off, csr_src, aggb, N);
    gemm_mfma<<<gemmGrid, 256, 0, stream>>>((const unsigned short*)aggb,
                                            (const unsigned short*)xb, Wc1, b1,
                                            nullptr, (unsigned short*)h1b, N, 1);
    // layer 2: agg(bf16 h1b)->aggb; MFMA gemm -> h2 (fp32 for lin3)
    agg_bf16<<<aggGrid, 256, 0, stream>>>((const uint*)h1b, row_off, csr_src, aggb, N);
    gemm_mfma<<<gemmGrid, 256, 0, stream>>>((const unsigned short*)aggb,
                                            (const unsigned short*)h1b, Wc2, b2,
                                            h2, nullptr, N, 1);
    // layer 3
    lin3_kernel<<<(N + 15) / 16, 256, 0, stream>>>(h2, Wl3, Wr3, b3, zr, N);
    out_kernel<<<(N * 8 + 255) / 256, 256, 0, stream>>>(zr, row_off, csr_src, (float*)d_out, N);
}

// Round 12
// 615.210 us; speedup vs baseline: 1.1224x; 1.0586x over previous
//
#include <hip/hip_runtime.h>
#include <hip/hip_bf16.h>

#define N_NODES 100000
#define G_PART 16     // node groups; npg = 6250 -> 25 KB LDS hist
#define B_PART 96     // blocks per group; grid 1536 = 6 blocks/CU (LDS cap)
#define NPG_PAD 6272  // LDS capacity (>= ceil(N/G_PART))
#define A_BLOCKS 1024 // partition blocks

// ---------------------------------------------------------------- CSR build
// R5: device atomics are memory-side -> LDS hist. R6: occupancy. R7: don't
// pollute L2 with the stream. R8: radix partition, edges read ~once.
// R12: partial counts are ushort (max ~60) -> halves count/scan/fill traffic.
__global__ __launch_bounds__(256) void partition_edges(
    const int* __restrict__ src, const int* __restrict__ dst, int E,
    int* __restrict__ bkt, unsigned int* __restrict__ gcur, int cap, int npg) {
    __shared__ int cnt16[G_PART];
    __shared__ unsigned int base16[G_PART];
    __shared__ unsigned int cur16[G_PART];
    int tid = threadIdx.x;
    if (tid < G_PART) cnt16[tid] = 0;
    __syncthreads();
    int per = (E + A_BLOCKS - 1) / A_BLOCKS;
    int beg = blockIdx.x * per;
    int end = min(beg + per, E);
    for (int i = beg + tid; i < end; i += 256) {
        int d = dst[i];
        atomicAdd(&cnt16[d / npg], 1);
    }
    __syncthreads();
    if (tid < G_PART) {
        base16[tid] = atomicAdd(&gcur[tid], (unsigned int)cnt16[tid]);
        cur16[tid] = 0;
    }
    __syncthreads();
    for (int i = beg + tid; i < end; i += 256) {
        int d = dst[i];
        int s = src[i];
        int g = d / npg;
        unsigned int p = base16[g] + atomicAdd(&cur16[g], 1u);
        bkt[(size_t)g * cap + p] = ((d - g * npg) << 17) | s;
    }
}

__global__ __launch_bounds__(256) void count_hist(const int* __restrict__ bkt,
                                                  const unsigned int* __restrict__ gcur,
                                                  int cap, unsigned short* __restrict__ partial,
                                                  int npg, int N) {
    __shared__ int hist[NPG_PAD];
    int g = blockIdx.x & (G_PART - 1);
    int b = blockIdx.x / G_PART;
    int tid = threadIdx.x;
    for (int i = tid; i < npg; i += 256) hist[i] = 0;
    __syncthreads();
    int len = (int)gcur[g];
    int per = (len + B_PART - 1) / B_PART;
    int ibeg = b * per;
    int iend = min(ibeg + per, len);
    const int* bp = bkt + (size_t)g * cap;
    for (int i = ibeg + tid; i < iend; i += 256) {
        int v = __builtin_nontemporal_load(bp + i);
        atomicAdd(&hist[v >> 17], 1);
    }
    __syncthreads();
    size_t base = (size_t)(g * B_PART + b) * npg;
    for (int j = tid; j < npg; j += 256) partial[base + j] = (unsigned short)hist[j];
}

__global__ __launch_bounds__(256) void scan_partials(unsigned short* __restrict__ partial,
                                                     int* __restrict__ cnt,
                                                     int npg, int N) {
    int n = blockIdx.x * 256 + threadIdx.x;
    if (n >= N) return;
    int g = n / npg;
    int i = n - g * npg;
    size_t base = (size_t)g * B_PART * npg + i;
    int run = 0;
#pragma unroll 4
    for (int b = 0; b < B_PART; ++b) {
        size_t idx = base + (size_t)b * npg;
        int t = partial[idx];
        partial[idx] = (unsigned short)run;
        run += t;
    }
    cnt[n] = run;
}

__global__ __launch_bounds__(256) void fill_hist(const int* __restrict__ bkt,
                                                 const unsigned int* __restrict__ gcur,
                                                 int cap,
                                                 const unsigned short* __restrict__ partial,
                                                 const int* __restrict__ row_off,
                                                 int* __restrict__ csr_src,
                                                 int npg, int N) {
    __shared__ int cur[NPG_PAD];
    int g = blockIdx.x & (G_PART - 1);
    int b = blockIdx.x / G_PART;
    int lo = g * npg;
    int tid = threadIdx.x;
    size_t pbase = (size_t)(g * B_PART + b) * npg;
    for (int i = tid; i < npg && lo + i < N; i += 256)
        cur[i] = row_off[lo + i] + (int)partial[pbase + i];
    __syncthreads();
    int len = (int)gcur[g];
    int per = (len + B_PART - 1) / B_PART;
    int ibeg = b * per;
    int iend = min(ibeg + per, len);
    const int* bp = bkt + (size_t)g * cap;
    for (int i = ibeg + tid; i < iend; i += 256) {
        int v = __builtin_nontemporal_load(bp + i);
        int p = atomicAdd(&cur[v >> 17], 1);
        csr_src[p] = v & 0x1FFFF;
    }
}

// ---------------- grid-parallel exclusive scan (3 kernels, 1024 elems/block)
#define SCHUNK 1024

__global__ __launch_bounds__(256) void scan_blocks(const int* __restrict__ cnt,
                                                   int* __restrict__ row_off,
                                                   int* __restrict__ block_sums, int n) {
    __shared__ int ts[256];
    int tid = threadIdx.x;
    int base = blockIdx.x * SCHUNK + tid * 4;
    int v[4];
    int s = 0;
#pragma unroll
    for (int j = 0; j < 4; ++j) {
        int i = base + j;
        v[j] = (i < n) ? cnt[i] : 0;
        s += v[j];
    }
    ts[tid] = s;
    __syncthreads();
    for (int off = 1; off < 256; off <<= 1) {
        int t = 0;
        if (tid >= off) t = ts[tid - off];
        __syncthreads();
        if (tid >= off) ts[tid] += t;
        __syncthreads();
    }
    int run = (tid > 0) ? ts[tid - 1] : 0;
    if (tid == 255) block_sums[blockIdx.x] = ts[255];
#pragma unroll
    for (int j = 0; j < 4; ++j) {
        int i = base + j;
        if (i < n) row_off[i] = run;
        run += v[j];
    }
}

__global__ __launch_bounds__(256) void scan_sums(int* __restrict__ block_sums, int nb,
                                                 int* __restrict__ row_off, int n) {
    __shared__ int ts[256];
    int tid = threadIdx.x;
    int v = (tid < nb) ? block_sums[tid] : 0;
    ts[tid] = v;
    __syncthreads();
    for (int off = 1; off < 256; off <<= 1) {
        int t = 0;
        if (tid >= off) t = ts[tid - off];
        __syncthreads();
        if (tid >= off) ts[tid] += t;
        __syncthreads();
    }
    if (tid < nb) block_sums[tid] = (tid > 0) ? ts[tid - 1] : 0;
    if (tid == 255) row_off[n] = ts[255];
}

__global__ __launch_bounds__(256) void scan_add(int* __restrict__ row_off,
                                                const int* __restrict__ block_sums, int n) {
    int tid = threadIdx.x;
    int off = block_sums[blockIdx.x];
    int base = blockIdx.x * SCHUNK + tid * 4;
#pragma unroll
    for (int j = 0; j < 4; ++j) {
        int i = base + j;
        if (i < n) row_off[i] += off;
    }
}

// ---------------------------------------------------------------- bf16 packs
__global__ __launch_bounds__(256) void pack_bf16(const float* __restrict__ in,
                                                 uint2* __restrict__ out, int n4) {
    int i = blockIdx.x * 256 + threadIdx.x;
    if (i >= n4) return;
    float4 v = *(const float4*)&in[(size_t)i * 4];
    __hip_bfloat162 p0 = __float22bfloat162_rn(make_float2(v.x, v.y));
    __hip_bfloat162 p1 = __float22bfloat162_rn(make_float2(v.z, v.w));
    uint2 o;
    o.x = *(const uint*)&p0;
    o.y = *(const uint*)&p1;
    out[i] = o;
}

static __device__ inline unsigned short f2bf(float v) {
    __hip_bfloat16 b = __float2bfloat16(v);
    return *(const unsigned short*)&b;
}

// all weights in one launch: Wc1/Wc2 [128][256] ([Wl|Wr]); W3c [16][128]
// (rows 0-5 Wl3, 6-11 Wr3, 12-15 zero)
__global__ __launch_bounds__(256) void pack_weights(
    const float* __restrict__ Wl1, const float* __restrict__ Wr1,
    const float* __restrict__ Wl2, const float* __restrict__ Wr2,
    const float* __restrict__ Wl3, const float* __restrict__ Wr3,
    unsigned short* __restrict__ Wc1, unsigned short* __restrict__ Wc2,
    unsigned short* __restrict__ W3c) {
    int idx = blockIdx.x * 256 + threadIdx.x;
    if (idx < 32768) {
        int n = idx >> 8, k = idx & 255;
        Wc1[idx] = f2bf((k < 128) ? Wl1[n * 128 + k] : Wr1[n * 128 + (k - 128)]);
    } else if (idx < 65536) {
        int t = idx - 32768;
        int n = t >> 8, k = t & 255;
        Wc2[t] = f2bf((k < 128) ? Wl2[n * 128 + k] : Wr2[n * 128 + (k - 128)]);
    } else if (idx < 65536 + 2048) {
        int t = idx - 65536;
        int n = t >> 7, k = t & 127;
        float v = (n < 6) ? Wl3[n * 128 + k] : ((n < 12) ? Wr3[(n - 6) * 128 + k] : 0.f);
        W3c[t] = f2bf(v);
    }
}

// ------------------------------------------------- mean aggregation, bf16 in/out
// (R9 form: gather is FETCH-byte-bound at ~3.2TB/s random-256B; proven R10)
static __device__ inline float2 unpack2(uint v) {
    float2 r;
    r.x = __uint_as_float(v << 16);
    r.y = __uint_as_float(v & 0xffff0000u);
    return r;
}

__global__ __launch_bounds__(256) void agg_bf16(const uint* __restrict__ featb,
                                                const int* __restrict__ row_off,
                                                const int* __restrict__ csr,
                                                uint* __restrict__ outb, int M) {
    int node = blockIdx.x * 4 + (threadIdx.x >> 6);
    if (node >= M) return;
    int lane = threadIdx.x & 63;
    int beg = row_off[node], end = row_off[node + 1];
    float sx = 0.f, sy = 0.f;
    int i = beg;
    for (; i + 4 <= end; i += 4) {
        int s0 = csr[i], s1 = csr[i + 1], s2 = csr[i + 2], s3 = csr[i + 3];
        uint v0 = featb[(size_t)s0 * 64 + lane];
        uint v1 = featb[(size_t)s1 * 64 + lane];
        uint v2 = featb[(size_t)s2 * 64 + lane];
        uint v3 = featb[(size_t)s3 * 64 + lane];
        float2 f0 = unpack2(v0), f1 = unpack2(v1), f2 = unpack2(v2), f3 = unpack2(v3);
        sx += f0.x + f1.x + f2.x + f3.x;
        sy += f0.y + f1.y + f2.y + f3.y;
    }
    for (; i < end; ++i) {
        uint v = featb[(size_t)csr[i] * 64 + lane];
        float2 f = unpack2(v);
        sx += f.x;
        sy += f.y;
    }
    float inv = (end > beg) ? 1.0f / (float)(end - beg) : 0.0f;
    __hip_bfloat162 p = __float22bfloat162_rn(make_float2(sx * inv, sy * inv));
    outb[(size_t)node * 64 + lane] = *(const uint*)&p;
}

// --------------------------------------------- MFMA bf16 GEMM (LDS-free)
typedef __attribute__((ext_vector_type(8))) short bfrag8;
typedef __attribute__((ext_vector_type(4))) float f32x4;

__global__ __launch_bounds__(256) void gemm_mfma(
    const unsigned short* __restrict__ Aagg,   // [M][128] bf16
    const unsigned short* __restrict__ Aself,  // [M][128] bf16
    const unsigned short* __restrict__ Wc,     // [128][256] bf16
    const float* __restrict__ bias,            // [128]
    unsigned short* __restrict__ outb,         // [M][128] bf16
    int M, int relu) {
    int wave = threadIdx.x >> 6;
    int lane = threadIdx.x & 63;
    int m0 = blockIdx.x * 64 + wave * 16;
    int mrow = lane & 15;
    int quad = lane >> 4;
    int row = m0 + mrow;
    int rclamp = (row < M) ? row : 0;

    f32x4 acc[8];
#pragma unroll
    for (int t = 0; t < 8; ++t) acc[t] = (f32x4){0.f, 0.f, 0.f, 0.f};

    const unsigned short* arow0 = Aagg + (size_t)rclamp * 128;
    const unsigned short* arow1 = Aself + (size_t)rclamp * 128;
#pragma unroll
    for (int ks = 0; ks < 8; ++ks) {
        int k0 = ks * 32;
        const unsigned short* ap =
            (k0 < 128) ? (arow0 + k0 + quad * 8) : (arow1 + (k0 - 128) + quad * 8);
        bfrag8 af = *(const bfrag8*)ap;
#pragma unroll
        for (int t = 0; t < 8; ++t) {
            const unsigned short* bp = Wc + (size_t)(t * 16 + mrow) * 256 + k0 + quad * 8;
            bfrag8 bf = *(const bfrag8*)bp;
            acc[t] = __builtin_amdgcn_mfma_f32_16x16x32_bf16(af, bf, acc[t], 0, 0, 0);
        }
    }
#pragma unroll
    for (int t = 0; t < 8; ++t) {
        int col = t * 16 + mrow;
        float bcol = bias[col];
#pragma unroll
        for (int r = 0; r < 4; ++r) {
            int orow = m0 + quad * 4 + r;
            if (orow < M) {
                float v = acc[t][r] + bcol;
                if (relu) v = fmaxf(v, 0.f);
                outb[(size_t)orow * 128 + col] = f2bf(v);
            }
        }
    }
}

// ------------------- layer 3 via MFMA: zg[n][0..5]=h2@Wl3^T (bf16, gathered),
// zs[n][0..5]=h2@Wr3^T+b3 (fp32, self). Single 16x16 N-tile, K=128.
__global__ __launch_bounds__(256) void lin3_mfma(
    const unsigned short* __restrict__ h2b,  // [M][128] bf16
    const unsigned short* __restrict__ W3c,  // [16][128] bf16
    const float* __restrict__ b3,            // [6]
    unsigned short* __restrict__ zg,         // [M][8] bf16 (cols 0-5 used)
    float* __restrict__ zs,                  // [M][6] fp32
    int M) {
    int wave = threadIdx.x >> 6;
    int lane = threadIdx.x & 63;
    int m0 = blockIdx.x * 64 + wave * 16;
    int mrow = lane & 15;
    int quad = lane >> 4;
    int row = m0 + mrow;
    int rclamp = (row < M) ? row : 0;
    f32x4 acc = (f32x4){0.f, 0.f, 0.f, 0.f};
    const unsigned short* arow = h2b + (size_t)rclamp * 128;
#pragma unroll
    for (int ks = 0; ks < 4; ++ks) {
        bfrag8 af = *(const bfrag8*)(arow + ks * 32 + quad * 8);
        bfrag8 bf = *(const bfrag8*)(W3c + (size_t)mrow * 128 + ks * 32 + quad * 8);
        acc = __builtin_amdgcn_mfma_f32_16x16x32_bf16(af, bf, acc, 0, 0, 0);
    }
    int col = mrow;
#pragma unroll
    for (int r = 0; r < 4; ++r) {
        int orow = m0 + quad * 4 + r;
        if (orow < M) {
            float v = acc[r];
            if (col < 6) {
                zg[(size_t)orow * 8 + col] = f2bf(v);
            } else if (col < 12) {
                zs[(size_t)orow * 6 + (col - 6)] = v + b3[col - 6];
            }
        }
    }
}

// ------------------------------------------- final: out[n][j] = mean_s zg[s][j] + zs[n][j]
__global__ void out_kernel(const unsigned short* __restrict__ zg,
                           const float* __restrict__ zs,
                           const int* __restrict__ row_off,
                           const int* __restrict__ csr,
                           float* __restrict__ out, int M) {
    int idx = blockIdx.x * blockDim.x + threadIdx.x;
    int node = idx >> 3;
    int j = idx & 7;
    if (node >= M || j >= 6) return;
    int beg = row_off[node], end = row_off[node + 1];
    float acc = 0.f;
    int i = beg;
    for (; i + 4 <= end; i += 4) {
        int s0 = csr[i], s1 = csr[i + 1], s2 = csr[i + 2], s3 = csr[i + 3];
        uint z0 = zg[(size_t)s0 * 8 + j];
        uint z1 = zg[(size_t)s1 * 8 + j];
        uint z2 = zg[(size_t)s2 * 8 + j];
        uint z3 = zg[(size_t)s3 * 8 + j];
        acc += __uint_as_float(z0 << 16) + __uint_as_float(z1 << 16) +
               __uint_as_float(z2 << 16) + __uint_as_float(z3 << 16);
    }
    for (; i < end; ++i) {
        uint z = zg[(size_t)csr[i] * 8 + j];
        acc += __uint_as_float(z << 16);
    }
    float inv = (end > beg) ? 1.0f / (float)(end - beg) : 0.0f;
    out[(size_t)node * 6 + j] = acc * inv + zs[(size_t)node * 6 + j];
}

// ---------------------------------------------------------------- launch
static inline size_t align_up(size_t x, size_t a) { return (x + a - 1) & ~(a - 1); }

extern "C" void kernel_launch(void* const* d_in, const int* in_sizes, int n_in,
                              void* d_out, int out_size, void* d_ws, size_t ws_size,
                              hipStream_t stream) {
    const float* x = (const float*)d_in[0];
    const int* ei = (const int*)d_in[1];
    const float* Wl1 = (const float*)d_in[2];
    const float* Wr1 = (const float*)d_in[3];
    const float* b1 = (const float*)d_in[4];
    const float* Wl2 = (const float*)d_in[5];
    const float* Wr2 = (const float*)d_in[6];
    const float* b2 = (const float*)d_in[7];
    const float* Wl3 = (const float*)d_in[8];
    const float* Wr3 = (const float*)d_in[9];
    const float* b3 = (const float*)d_in[10];

    const int N = in_sizes[0] / 128;   // 100000
    const int E = in_sizes[1] / 2;     // 3200000
    const int* src = ei;
    const int* dst = ei + E;

    // workspace layout
    char* ws = (char*)d_ws;
    size_t off = 0;
    int* cnt = (int*)(ws + off);        off = align_up(off + (size_t)N * 4, 512);
    int* row_off = (int*)(ws + off);    off = align_up(off + (size_t)(N + 1) * 4, 512);
    int* block_sums = (int*)(ws + off); off = align_up(off + 512 * 4, 512);
    unsigned int* gcur = (unsigned int*)(ws + off); off = align_up(off + 64 * 4, 512);
    unsigned short* Wc1 = (unsigned short*)(ws + off); off = align_up(off + 128 * 256 * 2, 512);
    unsigned short* Wc2 = (unsigned short*)(ws + off); off = align_up(off + 128 * 256 * 2, 512);
    unsigned short* W3c = (unsigned short*)(ws + off); off = align_up(off + 16 * 128 * 2, 512);
    int* csr_src = (int*)(ws + off);    off = align_up(off + (size_t)E * 4, 512);
    float* slotA = (float*)(ws + off);  off = align_up(off + (size_t)N * 128 * 4, 512);
    float* slotB = (float*)(ws + off);  off = align_up(off + (size_t)N * 128 * 4, 512);
    float* slotC = (float*)(ws + off);  off = align_up(off + (size_t)N * 128 * 4, 512);
    uint2* h1b = (uint2*)(ws + off);    off = align_up(off + (size_t)N * 128 * 2, 512);
    // aliases (lifetimes disjoint):
    //  slotA: partial ushort [count..fill] (16*96*6250*2 = 19.2MB);
    //         aggb [agg1..gemm1, agg2..gemm2] (25.6MB)
    //  slotB: bkt [partition..fill] (13.44MB); h2b [gemm2..lin3] (25.6MB)
    //  slotC: xb [pack..gemm1] (25.6MB); zg+zs [lin3..out] (1.6+2.4MB)
    unsigned short* partial = (unsigned short*)slotA;
    uint* aggb = (uint*)slotA;
    const int cap = 210000;
    int* bkt = (int*)slotB;
    unsigned short* h2b = (unsigned short*)slotB;
    uint2* xb = (uint2*)slotC;
    unsigned short* zg = (unsigned short*)slotC;
    float* zs = (float*)((char*)slotC + align_up((size_t)N * 8 * 2, 512));
    (void)ws_size;

    // --- CSR build: radix partition + LDS histogram, no per-edge global atomics
    const int npg = (N + G_PART - 1) / G_PART;       // 6250
    const int build_grid = G_PART * B_PART;          // 1536 = 6 blocks/CU

    hipMemsetAsync(gcur, 0, G_PART * 4, stream);
    partition_edges<<<A_BLOCKS, 256, 0, stream>>>(src, dst, E, bkt, gcur, cap, npg);
    count_hist<<<build_grid, 256, 0, stream>>>(bkt, gcur, cap, partial, npg, N);
    scan_partials<<<(N + 255) / 256, 256, 0, stream>>>(partial, cnt, npg, N);

    const int nscan = (N + SCHUNK - 1) / SCHUNK;
    scan_blocks<<<nscan, 256, 0, stream>>>(cnt, row_off, block_sums, N);
    scan_sums<<<1, 256, 0, stream>>>(block_sums, nscan, row_off, N);
    scan_add<<<nscan, 256, 0, stream>>>(row_off, block_sums, N);

    fill_hist<<<build_grid, 256, 0, stream>>>(bkt, gcur, cap, partial, row_off,
                                              csr_src, npg, N);

    // packs
    const int n4 = N * 32;
    pack_bf16<<<(n4 + 255) / 256, 256, 0, stream>>>(x, xb, n4);
    pack_weights<<<(65536 + 2048 + 255) / 256, 256, 0, stream>>>(
        Wl1, Wr1, Wl2, Wr2, Wl3, Wr3, Wc1, Wc2, W3c);

    int aggGrid = (N + 3) / 4;
    int gemmGrid = (N + 63) / 64;

    // layer 1: agg(bf16)->aggb; MFMA gemm -> h1b (bf16)
    agg_bf16<<<aggGrid, 256, 0, stream>>>((const uint*)xb, row_off, csr_src, aggb, N);
    gemm_mfma<<<gemmGrid, 256, 0, stream>>>((const unsigned short*)aggb,
                                            (const unsigned short*)xb, Wc1, b1,
                                            (unsigned short*)h1b, N, 1);
    // layer 2: agg(bf16 h1b)->aggb; MFMA gemm -> h2b (bf16)
    agg_bf16<<<aggGrid, 256, 0, stream>>>((const uint*)h1b, row_off, csr_src, aggb, N);
    gemm_mfma<<<gemmGrid, 256, 0, stream>>>((const unsigned short*)aggb,
                                            (const unsigned short*)h1b, Wc2, b2,
                                            h2b, N, 1);
    // layer 3: MFMA mini-gemm -> zg (bf16 gather part) + zs (fp32 self part)
    lin3_mfma<<<gemmGrid, 256, 0, stream>>>(h2b, W3c, b3, zg, zs, N);
    out_kernel<<<(N * 8 + 255) / 256, 256, 0, stream>>>(zg, zs, row_off, csr_src,
                                                        (float*)d_out, N);
}

// Round 13
// 588.844 us; speedup vs baseline: 1.1726x; 1.0448x over previous
//
#include <hip/hip_runtime.h>
#include <hip/hip_bf16.h>

#define N_NODES 100000
#define G_PART 16     // node groups; npg = 6250 -> 25 KB LDS hist
#define B_PART 96     // blocks per group; grid 1536 = 6 blocks/CU (LDS cap)
#define NPG_PAD 6272  // LDS capacity (>= ceil(N/G_PART))
#define A_BLOCKS 1024 // partition blocks

// ---------------------------------------------------------------- CSR build
// R5: device atomics are memory-side -> LDS hist. R6: occupancy. R7: don't
// pollute L2 with the stream. R8: radix partition, edges read ~once.
// R12: ushort partials. R13: agg+gemm fused (see below).
__global__ __launch_bounds__(256) void partition_edges(
    const int* __restrict__ src, const int* __restrict__ dst, int E,
    int* __restrict__ bkt, unsigned int* __restrict__ gcur, int cap, int npg) {
    __shared__ int cnt16[G_PART];
    __shared__ unsigned int base16[G_PART];
    __shared__ unsigned int cur16[G_PART];
    int tid = threadIdx.x;
    if (tid < G_PART) cnt16[tid] = 0;
    __syncthreads();
    int per = (E + A_BLOCKS - 1) / A_BLOCKS;
    int beg = blockIdx.x * per;
    int end = min(beg + per, E);
    for (int i = beg + tid; i < end; i += 256) {
        int d = dst[i];
        atomicAdd(&cnt16[d / npg], 1);
    }
    __syncthreads();
    if (tid < G_PART) {
        base16[tid] = atomicAdd(&gcur[tid], (unsigned int)cnt16[tid]);
        cur16[tid] = 0;
    }
    __syncthreads();
    for (int i = beg + tid; i < end; i += 256) {
        int d = dst[i];
        int s = src[i];
        int g = d / npg;
        unsigned int p = base16[g] + atomicAdd(&cur16[g], 1u);
        bkt[(size_t)g * cap + p] = ((d - g * npg) << 17) | s;
    }
}

__global__ __launch_bounds__(256) void count_hist(const int* __restrict__ bkt,
                                                  const unsigned int* __restrict__ gcur,
                                                  int cap, unsigned short* __restrict__ partial,
                                                  int npg, int N) {
    __shared__ int hist[NPG_PAD];
    int g = blockIdx.x & (G_PART - 1);
    int b = blockIdx.x / G_PART;
    int tid = threadIdx.x;
    for (int i = tid; i < npg; i += 256) hist[i] = 0;
    __syncthreads();
    int len = (int)gcur[g];
    int per = (len + B_PART - 1) / B_PART;
    int ibeg = b * per;
    int iend = min(ibeg + per, len);
    const int* bp = bkt + (size_t)g * cap;
    for (int i = ibeg + tid; i < iend; i += 256) {
        int v = __builtin_nontemporal_load(bp + i);
        atomicAdd(&hist[v >> 17], 1);
    }
    __syncthreads();
    size_t base = (size_t)(g * B_PART + b) * npg;
    for (int j = tid; j < npg; j += 256) partial[base + j] = (unsigned short)hist[j];
}

__global__ __launch_bounds__(256) void scan_partials(unsigned short* __restrict__ partial,
                                                     int* __restrict__ cnt,
                                                     int npg, int N) {
    int n = blockIdx.x * 256 + threadIdx.x;
    if (n >= N) return;
    int g = n / npg;
    int i = n - g * npg;
    size_t base = (size_t)g * B_PART * npg + i;
    int run = 0;
#pragma unroll 4
    for (int b = 0; b < B_PART; ++b) {
        size_t idx = base + (size_t)b * npg;
        int t = partial[idx];
        partial[idx] = (unsigned short)run;
        run += t;
    }
    cnt[n] = run;
}

__global__ __launch_bounds__(256) void fill_hist(const int* __restrict__ bkt,
                                                 const unsigned int* __restrict__ gcur,
                                                 int cap,
                                                 const unsigned short* __restrict__ partial,
                                                 const int* __restrict__ row_off,
                                                 int* __restrict__ csr_src,
                                                 int npg, int N) {
    __shared__ int cur[NPG_PAD];
    int g = blockIdx.x & (G_PART - 1);
    int b = blockIdx.x / G_PART;
    int lo = g * npg;
    int tid = threadIdx.x;
    size_t pbase = (size_t)(g * B_PART + b) * npg;
    for (int i = tid; i < npg && lo + i < N; i += 256)
        cur[i] = row_off[lo + i] + (int)partial[pbase + i];
    __syncthreads();
    int len = (int)gcur[g];
    int per = (len + B_PART - 1) / B_PART;
    int ibeg = b * per;
    int iend = min(ibeg + per, len);
    const int* bp = bkt + (size_t)g * cap;
    for (int i = ibeg + tid; i < iend; i += 256) {
        int v = __builtin_nontemporal_load(bp + i);
        int p = atomicAdd(&cur[v >> 17], 1);
        csr_src[p] = v & 0x1FFFF;
    }
}

// ---------------- grid-parallel exclusive scan (3 kernels, 1024 elems/block)
#define SCHUNK 1024

__global__ __launch_bounds__(256) void scan_blocks(const int* __restrict__ cnt,
                                                   int* __restrict__ row_off,
                                                   int* __restrict__ block_sums, int n) {
    __shared__ int ts[256];
    int tid = threadIdx.x;
    int base = blockIdx.x * SCHUNK + tid * 4;
    int v[4];
    int s = 0;
#pragma unroll
    for (int j = 0; j < 4; ++j) {
        int i = base + j;
        v[j] = (i < n) ? cnt[i] : 0;
        s += v[j];
    }
    ts[tid] = s;
    __syncthreads();
    for (int off = 1; off < 256; off <<= 1) {
        int t = 0;
        if (tid >= off) t = ts[tid - off];
        __syncthreads();
        if (tid >= off) ts[tid] += t;
        __syncthreads();
    }
    int run = (tid > 0) ? ts[tid - 1] : 0;
    if (tid == 255) block_sums[blockIdx.x] = ts[255];
#pragma unroll
    for (int j = 0; j < 4; ++j) {
        int i = base + j;
        if (i < n) row_off[i] = run;
        run += v[j];
    }
}

__global__ __launch_bounds__(256) void scan_sums(int* __restrict__ block_sums, int nb,
                                                 int* __restrict__ row_off, int n) {
    __shared__ int ts[256];
    int tid = threadIdx.x;
    int v = (tid < nb) ? block_sums[tid] : 0;
    ts[tid] = v;
    __syncthreads();
    for (int off = 1; off < 256; off <<= 1) {
        int t = 0;
        if (tid >= off) t = ts[tid - off];
        __syncthreads();
        if (tid >= off) ts[tid] += t;
        __syncthreads();
    }
    if (tid < nb) block_sums[tid] = (tid > 0) ? ts[tid - 1] : 0;
    if (tid == 255) row_off[n] = ts[255];
}

__global__ __launch_bounds__(256) void scan_add(int* __restrict__ row_off,
                                                const int* __restrict__ block_sums, int n) {
    int tid = threadIdx.x;
    int off = block_sums[blockIdx.x];
    int base = blockIdx.x * SCHUNK + tid * 4;
#pragma unroll
    for (int j = 0; j < 4; ++j) {
        int i = base + j;
        if (i < n) row_off[i] += off;
    }
}

// ---------------------------------------------------------------- bf16 packs
__global__ __launch_bounds__(256) void pack_bf16(const float* __restrict__ in,
                                                 uint2* __restrict__ out, int n4) {
    int i = blockIdx.x * 256 + threadIdx.x;
    if (i >= n4) return;
    float4 v = *(const float4*)&in[(size_t)i * 4];
    __hip_bfloat162 p0 = __float22bfloat162_rn(make_float2(v.x, v.y));
    __hip_bfloat162 p1 = __float22bfloat162_rn(make_float2(v.z, v.w));
    uint2 o;
    o.x = *(const uint*)&p0;
    o.y = *(const uint*)&p1;
    out[i] = o;
}

static __device__ inline unsigned short f2bf(float v) {
    __hip_bfloat16 b = __float2bfloat16(v);
    return *(const unsigned short*)&b;
}

// all weights in one launch: Wc1/Wc2 [128][256] ([Wl|Wr]); W3c [16][128]
__global__ __launch_bounds__(256) void pack_weights(
    const float* __restrict__ Wl1, const float* __restrict__ Wr1,
    const float* __restrict__ Wl2, const float* __restrict__ Wr2,
    const float* __restrict__ Wl3, const float* __restrict__ Wr3,
    unsigned short* __restrict__ Wc1, unsigned short* __restrict__ Wc2,
    unsigned short* __restrict__ W3c) {
    int idx = blockIdx.x * 256 + threadIdx.x;
    if (idx < 32768) {
        int n = idx >> 8, k = idx & 255;
        Wc1[idx] = f2bf((k < 128) ? Wl1[n * 128 + k] : Wr1[n * 128 + (k - 128)]);
    } else if (idx < 65536) {
        int t = idx - 32768;
        int n = t >> 8, k = t & 255;
        Wc2[t] = f2bf((k < 128) ? Wl2[n * 128 + k] : Wr2[n * 128 + (k - 128)]);
    } else if (idx < 65536 + 2048) {
        int t = idx - 65536;
        int n = t >> 7, k = t & 127;
        float v = (n < 6) ? Wl3[n * 128 + k] : ((n < 12) ? Wr3[(n - 6) * 128 + k] : 0.f);
        W3c[t] = f2bf(v);
    }
}

// --------------------------------------------- fused agg + MFMA GEMM (+lin3)
// R13: per block of 16 nodes: phase 1 gathers mean-agg rows (R9 loop, bf16)
// into LDS; phase 2 runs the LDS-free MFMA tile (M=16,N=128,K=256; A-half
// from LDS, self-half + W from global). Kills the aggb 51.2MB round trip per
// layer. Layer 2 additionally round-trips the h2 tile through LDS and runs
// the K=128 lin3 MFMA in-block -> zg/zs directly (h2b never materialized).
typedef __attribute__((ext_vector_type(8))) short bfrag8;
typedef __attribute__((ext_vector_type(4))) float f32x4;

static __device__ inline float2 unpack2(uint v) {
    float2 r;
    r.x = __uint_as_float(v << 16);
    r.y = __uint_as_float(v & 0xffff0000u);
    return r;
}

__global__ __launch_bounds__(256) void agg_gemm(
    const uint* __restrict__ featb,           // [N][64] bf16x2 gather table
    const unsigned short* __restrict__ Aself, // [M][128] bf16 self rows
    const int* __restrict__ row_off,
    const int* __restrict__ csr,
    const unsigned short* __restrict__ Wc,    // [128][256] bf16
    const float* __restrict__ bias,           // [128]
    unsigned short* __restrict__ outb,        // [M][128] bf16 (nullable)
    int do_lin3,
    const unsigned short* __restrict__ W3c,   // [16][128] bf16
    const float* __restrict__ b3,             // [6]
    unsigned short* __restrict__ zg,          // [M][8] bf16
    float* __restrict__ zs,                   // [M][6] fp32
    int M, int relu) {
    __shared__ unsigned short aggT[16][136];  // +8 pad
    __shared__ unsigned short h2T[16][136];
    int tid = threadIdx.x;
    int wave = tid >> 6;
    int lane = tid & 63;
    int tile = blockIdx.x * 16;

    // ---- phase 1: gather (4 nodes per wave, sequential; R9 inner loop)
    for (int sub = 0; sub < 4; ++sub) {
        int node = tile + wave * 4 + sub;
        float sx = 0.f, sy = 0.f;
        float inv = 0.f;
        if (node < M) {
            int beg = row_off[node], end = row_off[node + 1];
            int i = beg;
            for (; i + 4 <= end; i += 4) {
                int s0 = csr[i], s1 = csr[i + 1], s2 = csr[i + 2], s3 = csr[i + 3];
                uint v0 = featb[(size_t)s0 * 64 + lane];
                uint v1 = featb[(size_t)s1 * 64 + lane];
                uint v2 = featb[(size_t)s2 * 64 + lane];
                uint v3 = featb[(size_t)s3 * 64 + lane];
                float2 f0 = unpack2(v0), f1 = unpack2(v1);
                float2 f2 = unpack2(v2), f3 = unpack2(v3);
                sx += f0.x + f1.x + f2.x + f3.x;
                sy += f0.y + f1.y + f2.y + f3.y;
            }
            for (; i < end; ++i) {
                uint v = featb[(size_t)csr[i] * 64 + lane];
                float2 f = unpack2(v);
                sx += f.x;
                sy += f.y;
            }
            inv = (end > beg) ? 1.0f / (float)(end - beg) : 0.0f;
        }
        __hip_bfloat162 p = __float22bfloat162_rn(make_float2(sx * inv, sy * inv));
        *(uint*)&aggT[wave * 4 + sub][lane * 2] = *(const uint*)&p;
    }
    __syncthreads();

    // ---- phase 2: MFMA tile. wave w covers cols 32w..32w+31 (t = 2w, 2w+1)
    int mrow = lane & 15;
    int quad = lane >> 4;
    int row = tile + mrow;
    int rc = (row < M) ? row : 0;
    f32x4 acc0 = (f32x4){0.f, 0.f, 0.f, 0.f};
    f32x4 acc1 = (f32x4){0.f, 0.f, 0.f, 0.f};
    const unsigned short* arow1 = Aself + (size_t)rc * 128;
    int t0 = wave * 2, t1 = wave * 2 + 1;
#pragma unroll
    for (int ks = 0; ks < 8; ++ks) {
        bfrag8 af;
        if (ks < 4) af = *(const bfrag8*)&aggT[mrow][ks * 32 + quad * 8];
        else af = *(const bfrag8*)(arow1 + (ks - 4) * 32 + quad * 8);
        bfrag8 bf0 = *(const bfrag8*)(Wc + (size_t)(t0 * 16 + mrow) * 256 + ks * 32 + quad * 8);
        bfrag8 bf1 = *(const bfrag8*)(Wc + (size_t)(t1 * 16 + mrow) * 256 + ks * 32 + quad * 8);
        acc0 = __builtin_amdgcn_mfma_f32_16x16x32_bf16(af, bf0, acc0, 0, 0, 0);
        acc1 = __builtin_amdgcn_mfma_f32_16x16x32_bf16(af, bf1, acc1, 0, 0, 0);
    }
    // epilogue: C layout col=lane&15 (within t-tile), row=quad*4+r
#pragma unroll
    for (int tt = 0; tt < 2; ++tt) {
        f32x4 a = tt ? acc1 : acc0;
        int t = wave * 2 + tt;
        int col = t * 16 + mrow;
        float bc = bias[col];
#pragma unroll
        for (int r = 0; r < 4; ++r) {
            int orow = tile + quad * 4 + r;
            float v = a[r] + bc;
            if (relu) v = fmaxf(v, 0.f);
            unsigned short hv = f2bf(v);
            if (outb && orow < M) outb[(size_t)orow * 128 + col] = hv;
            if (do_lin3) h2T[quad * 4 + r][col] = hv;
        }
    }
    // ---- fused lin3 (layer 2 only): C->A via LDS, one 16x16 tile, K=128
    if (do_lin3) {
        __syncthreads();
        if (wave == 0) {
            f32x4 acc = (f32x4){0.f, 0.f, 0.f, 0.f};
#pragma unroll
            for (int ks = 0; ks < 4; ++ks) {
                bfrag8 af = *(const bfrag8*)&h2T[mrow][ks * 32 + quad * 8];
                bfrag8 bf = *(const bfrag8*)(W3c + (size_t)mrow * 128 + ks * 32 + quad * 8);
                acc = __builtin_amdgcn_mfma_f32_16x16x32_bf16(af, bf, acc, 0, 0, 0);
            }
            int col = mrow;
#pragma unroll
            for (int r = 0; r < 4; ++r) {
                int orow = tile + quad * 4 + r;
                if (orow < M) {
                    float v = acc[r];
                    if (col < 6) {
                        zg[(size_t)orow * 8 + col] = f2bf(v);
                    } else if (col < 12) {
                        zs[(size_t)orow * 6 + (col - 6)] = v + b3[col - 6];
                    }
                }
            }
        }
    }
}

// ------------------------------------------- final: out[n][j] = mean_s zg[s][j] + zs[n][j]
__global__ void out_kernel(const unsigned short* __restrict__ zg,
                           const float* __restrict__ zs,
                           const int* __restrict__ row_off,
                           const int* __restrict__ csr,
                           float* __restrict__ out, int M) {
    int idx = blockIdx.x * blockDim.x + threadIdx.x;
    int node = idx >> 3;
    int j = idx & 7;
    if (node >= M || j >= 6) return;
    int beg = row_off[node], end = row_off[node + 1];
    float acc = 0.f;
    int i = beg;
    for (; i + 4 <= end; i += 4) {
        int s0 = csr[i], s1 = csr[i + 1], s2 = csr[i + 2], s3 = csr[i + 3];
        uint z0 = zg[(size_t)s0 * 8 + j];
        uint z1 = zg[(size_t)s1 * 8 + j];
        uint z2 = zg[(size_t)s2 * 8 + j];
        uint z3 = zg[(size_t)s3 * 8 + j];
        acc += __uint_as_float(z0 << 16) + __uint_as_float(z1 << 16) +
               __uint_as_float(z2 << 16) + __uint_as_float(z3 << 16);
    }
    for (; i < end; ++i) {
        uint z = zg[(size_t)csr[i] * 8 + j];
        acc += __uint_as_float(z << 16);
    }
    float inv = (end > beg) ? 1.0f / (float)(end - beg) : 0.0f;
    out[(size_t)node * 6 + j] = acc * inv + zs[(size_t)node * 6 + j];
}

// ---------------------------------------------------------------- launch
static inline size_t align_up(size_t x, size_t a) { return (x + a - 1) & ~(a - 1); }

extern "C" void kernel_launch(void* const* d_in, const int* in_sizes, int n_in,
                              void* d_out, int out_size, void* d_ws, size_t ws_size,
                              hipStream_t stream) {
    const float* x = (const float*)d_in[0];
    const int* ei = (const int*)d_in[1];
    const float* Wl1 = (const float*)d_in[2];
    const float* Wr1 = (const float*)d_in[3];
    const float* b1 = (const float*)d_in[4];
    const float* Wl2 = (const float*)d_in[5];
    const float* Wr2 = (const float*)d_in[6];
    const float* b2 = (const float*)d_in[7];
    const float* Wl3 = (const float*)d_in[8];
    const float* Wr3 = (const float*)d_in[9];
    const float* b3 = (const float*)d_in[10];

    const int N = in_sizes[0] / 128;   // 100000
    const int E = in_sizes[1] / 2;     // 3200000
    const int* src = ei;
    const int* dst = ei + E;

    // workspace layout
    char* ws = (char*)d_ws;
    size_t off = 0;
    int* cnt = (int*)(ws + off);        off = align_up(off + (size_t)N * 4, 512);
    int* row_off = (int*)(ws + off);    off = align_up(off + (size_t)(N + 1) * 4, 512);
    int* block_sums = (int*)(ws + off); off = align_up(off + 512 * 4, 512);
    unsigned int* gcur = (unsigned int*)(ws + off); off = align_up(off + 64 * 4, 512);
    unsigned short* Wc1 = (unsigned short*)(ws + off); off = align_up(off + 128 * 256 * 2, 512);
    unsigned short* Wc2 = (unsigned short*)(ws + off); off = align_up(off + 128 * 256 * 2, 512);
    unsigned short* W3c = (unsigned short*)(ws + off); off = align_up(off + 16 * 128 * 2, 512);
    int* csr_src = (int*)(ws + off);    off = align_up(off + (size_t)E * 4, 512);
    float* slotA = (float*)(ws + off);  off = align_up(off + (size_t)N * 128 * 4, 512);
    float* slotB = (float*)(ws + off);  off = align_up(off + (size_t)N * 128 * 4, 512);
    uint2* h1b = (uint2*)(ws + off);    off = align_up(off + (size_t)N * 128 * 2, 512);
    // aliases (lifetimes disjoint):
    //  slotA: partial ushort [count..fill] (19.2MB)
    //  slotB: bkt [partition..fill] (13.44MB); zg+zs [agg_gemm2..out] (4MB)
    //  slotA also: xb [pack..agg_gemm1] (25.6MB)
    unsigned short* partial = (unsigned short*)slotA;
    const int cap = 210000;
    int* bkt = (int*)slotB;
    uint2* xb = (uint2*)slotA;          // written after fill (partial dead)
    unsigned short* zg = (unsigned short*)slotB;
    float* zs = (float*)((char*)slotB + align_up((size_t)N * 8 * 2, 512));
    (void)ws_size;

    // --- CSR build: radix partition + LDS histogram, no per-edge global atomics
    const int npg = (N + G_PART - 1) / G_PART;       // 6250
    const int build_grid = G_PART * B_PART;          // 1536 = 6 blocks/CU

    hipMemsetAsync(gcur, 0, G_PART * 4, stream);
    partition_edges<<<A_BLOCKS, 256, 0, stream>>>(src, dst, E, bkt, gcur, cap, npg);
    count_hist<<<build_grid, 256, 0, stream>>>(bkt, gcur, cap, partial, npg, N);
    scan_partials<<<(N + 255) / 256, 256, 0, stream>>>(partial, cnt, npg, N);

    const int nscan = (N + SCHUNK - 1) / SCHUNK;
    scan_blocks<<<nscan, 256, 0, stream>>>(cnt, row_off, block_sums, N);
    scan_sums<<<1, 256, 0, stream>>>(block_sums, nscan, row_off, N);
    scan_add<<<nscan, 256, 0, stream>>>(row_off, block_sums, N);

    fill_hist<<<build_grid, 256, 0, stream>>>(bkt, gcur, cap, partial, row_off,
                                              csr_src, npg, N);

    // packs (xb after fill: partial/aggb slot is free)
    const int n4 = N * 32;
    pack_bf16<<<(n4 + 255) / 256, 256, 0, stream>>>(x, xb, n4);
    pack_weights<<<(65536 + 2048 + 255) / 256, 256, 0, stream>>>(
        Wl1, Wr1, Wl2, Wr2, Wl3, Wr3, Wc1, Wc2, W3c);

    int fusedGrid = (N + 15) / 16;   // 6250 blocks

    // layer 1: fused gather+GEMM -> h1b (bf16)
    agg_gemm<<<fusedGrid, 256, 0, stream>>>(
        (const uint*)xb, (const unsigned short*)xb, row_off, csr_src, Wc1, b1,
        (unsigned short*)h1b, 0, nullptr, nullptr, nullptr, nullptr, N, 1);
    // layer 2: fused gather+GEMM+lin3 -> zg (bf16) + zs (fp32); h2 never stored
    agg_gemm<<<fusedGrid, 256, 0, stream>>>(
        (const uint*)h1b, (const unsigned short*)h1b, row_off, csr_src, Wc2, b2,
        nullptr, 1, W3c, b3, zg, zs, N, 1);
    // final
    out_kernel<<<(N * 8 + 255) / 256, 256, 0, stream>>>(zg, zs, row_off, csr_src,
                                                        (float*)d_out, N);
}